// Round 1
// baseline (3738.620 us; speedup 1.0000x reference)
//
#include <hip/hip_runtime.h>
#include <hip/hip_bf16.h>

#define EMB 768
#define HID 3072
#define HID2 6144
#define NE 8
#define TOK 16384    // B*N = 8*2048
#define SLOTS 32768  // TOK * top-2
#define SLACK 128    // tail-read slack rows

typedef __attribute__((ext_vector_type(8))) short bf16x8;
typedef __attribute__((ext_vector_type(4))) float f32x4;

__device__ __forceinline__ unsigned short bfbits(float f) {
  __hip_bfloat16 h = __float2bfloat16(f);
  return __builtin_bit_cast(unsigned short, h);
}

// ---------------- init / gating / routing ----------------

__global__ void k_init(int* counts, int* fill) {
  if (threadIdx.x < NE) { counts[threadIdx.x] = 0; fill[threadIdx.x] = 0; }
}

__global__ __launch_bounds__(256) void k_gating(
    const float* __restrict__ x, const float* __restrict__ Wg,
    const float* __restrict__ bg, int* __restrict__ eidx,
    float* __restrict__ gates, int* __restrict__ counts)
{
  const int wave = threadIdx.x >> 6, lane = threadIdx.x & 63;
  const int t = blockIdx.x * 4 + wave;
  const float* xr = x + (size_t)t * EMB;
  float p[NE];
#pragma unroll
  for (int e = 0; e < NE; ++e) p[e] = 0.f;
  for (int k = lane; k < EMB; k += 64) {
    const float xv = xr[k];
    const float* wr = Wg + (size_t)k * NE;
#pragma unroll
    for (int e = 0; e < NE; ++e) p[e] += xv * wr[e];
  }
#pragma unroll
  for (int e = 0; e < NE; ++e) {
#pragma unroll
    for (int o = 32; o > 0; o >>= 1) p[e] += __shfl_xor(p[e], o);
    p[e] += bg[e];
  }
  // top-2, first-index tie-break (matches lax.top_k)
  float v0 = -1e30f, v1 = -1e30f; int i0 = 0, i1 = 0;
#pragma unroll
  for (int e = 0; e < NE; ++e) {
    const float v = p[e];
    if (v > v0)      { v1 = v0; i1 = i0; v0 = v; i0 = e; }
    else if (v > v1) { v1 = v;  i1 = e; }
  }
  const float ex = expf(v1 - v0);
  const float g0 = 1.f / (1.f + ex);
  const float g1 = 1.f - g0;
  if (lane == 0) {
    eidx[2*t] = i0; eidx[2*t+1] = i1;
    gates[2*t] = g0; gates[2*t+1] = g1;
    atomicAdd(&counts[i0], 1);
    atomicAdd(&counts[i1], 1);
  }
}

__global__ void k_offsets(const int* __restrict__ counts, int* __restrict__ offsets) {
  offsets[0] = 0;
  for (int e = 0; e < NE; ++e) offsets[e+1] = offsets[e] + counts[e];
}

__global__ void k_route(const int* __restrict__ eidx, int* __restrict__ fill,
                        const int* __restrict__ offsets, int* __restrict__ route_tok,
                        int* __restrict__ slot_of)
{
  const int t = blockIdx.x * 256 + threadIdx.x;
  if (t >= TOK) return;
#pragma unroll
  for (int k = 0; k < 2; ++k) {
    const int e = eidx[2*t + k];
    const int pos = atomicAdd(&fill[e], 1);
    const int slot = offsets[e] + pos;
    route_tok[slot] = t;
    slot_of[2*t + k] = slot;
  }
}

// gather x rows (fp32) into compacted bf16 A-matrix
__global__ void k_gather(const float* __restrict__ x, const int* __restrict__ route_tok,
                         __hip_bfloat16* __restrict__ xg)
{
  const int s = blockIdx.x;
  const int t = route_tok[s];
  const float4 v = ((const float4*)(x + (size_t)t * EMB))[threadIdx.x];
  ushort4 u;
  u.x = bfbits(v.x); u.y = bfbits(v.y); u.z = bfbits(v.z); u.w = bfbits(v.w);
  *(ushort4*)((unsigned short*)xg + (size_t)s * EMB + threadIdx.x * 4) = u;
}

// fp32 [K,N] -> bf16 [N,K]  (per expert, LDS-tiled transpose)
__global__ void k_transpose(const float* __restrict__ W, __hip_bfloat16* __restrict__ Wt,
                            int K, int N)
{
  __shared__ float tile[32][33];
  const int e = blockIdx.z;
  const float* Wp = W + (size_t)e * K * N;
  __hip_bfloat16* Wtp = Wt + (size_t)e * K * N;
  const int n0 = blockIdx.x * 32, k0 = blockIdx.y * 32;
  for (int r = threadIdx.y; r < 32; r += 8)
    tile[r][threadIdx.x] = Wp[(size_t)(k0 + r) * N + n0 + threadIdx.x];
  __syncthreads();
  for (int r = threadIdx.y; r < 32; r += 8)
    Wtp[(size_t)(n0 + r) * K + k0 + threadIdx.x] = __float2bfloat16(tile[threadIdx.x][r]);
}

// ---------------- MFMA GEMM: C[m,n] = act(A[m,:] @ Bt[n,:] + bias[n]) ----------------
// A: bf16 [slots, K] row-major (segment per expert); Bt: bf16 [NE, N, K] (transposed weight)
// 128x128 tile, 4 waves (2x2), each wave 64x64 via 4x4 of 16x16x32 MFMA, BK=32.

template<bool GELU, bool OUTBF>
__global__ __launch_bounds__(256) void ffn_gemm(
    const __hip_bfloat16* __restrict__ A,
    const __hip_bfloat16* __restrict__ Bt,
    const float* __restrict__ bias,
    void* __restrict__ Cout,
    const int* __restrict__ counts,
    const int* __restrict__ offsets,
    int K, int N)
{
  const int e = blockIdx.z;
  const int cnt = counts[e];
  const int m0 = blockIdx.y * 128;
  if (m0 >= cnt) return;
  const int seg = offsets[e];
  const int n0 = blockIdx.x * 128;

  __shared__ __hip_bfloat16 Al[128 * 32];
  __shared__ __hip_bfloat16 Bl[128 * 32];

  const int tid = threadIdx.x;
  const int wave = tid >> 6;
  const int lane = tid & 63;

  const __hip_bfloat16* Ag = A + (size_t)(seg + m0) * K;
  const __hip_bfloat16* Bg = Bt + (size_t)e * N * K + (size_t)n0 * K;

  // staging: chunk = 16 rows x 32 cols (1 KiB). wave w stages rows [w*16, w*16+16) and +64.
  const int srow = wave * 16 + (lane >> 2);
  const int skc  = (lane & 3) * 8;

  const int wm = wave >> 1, wn = wave & 1;
  const int fr = lane & 15;          // M-row (A) / N-col (B) within 16x16 frag
  const int fk = (lane >> 4) * 8;    // k-block of 8

  f32x4 acc[4][4];
#pragma unroll
  for (int i = 0; i < 4; ++i)
#pragma unroll
    for (int j = 0; j < 4; ++j)
      acc[i][j] = (f32x4){0.f, 0.f, 0.f, 0.f};

  const int KT = K >> 5;
  for (int kt = 0; kt < KT; ++kt) {
    const int kb = kt * 32;
    __syncthreads();
    __builtin_amdgcn_global_load_lds(
        (const __attribute__((address_space(1))) void*)(Ag + (size_t)srow * K + kb + skc),
        (__attribute__((address_space(3))) void*)(Al + wave * 512), 16, 0, 0);
    __builtin_amdgcn_global_load_lds(
        (const __attribute__((address_space(1))) void*)(Ag + (size_t)(srow + 64) * K + kb + skc),
        (__attribute__((address_space(3))) void*)(Al + wave * 512 + 2048), 16, 0, 0);
    __builtin_amdgcn_global_load_lds(
        (const __attribute__((address_space(1))) void*)(Bg + (size_t)srow * K + kb + skc),
        (__attribute__((address_space(3))) void*)(Bl + wave * 512), 16, 0, 0);
    __builtin_amdgcn_global_load_lds(
        (const __attribute__((address_space(1))) void*)(Bg + (size_t)(srow + 64) * K + kb + skc),
        (__attribute__((address_space(3))) void*)(Bl + wave * 512 + 2048), 16, 0, 0);
    __syncthreads();

    bf16x8 a[4], b[4];
#pragma unroll
    for (int i = 0; i < 4; ++i)
      a[i] = *(const bf16x8*)(Al + (wm * 64 + i * 16 + fr) * 32 + fk);
#pragma unroll
    for (int j = 0; j < 4; ++j)
      b[j] = *(const bf16x8*)(Bl + (wn * 64 + j * 16 + fr) * 32 + fk);
#pragma unroll
    for (int i = 0; i < 4; ++i)
#pragma unroll
      for (int j = 0; j < 4; ++j)
        acc[i][j] = __builtin_amdgcn_mfma_f32_16x16x32_bf16(a[i], b[j], acc[i][j], 0, 0, 0);
  }

  // epilogue: C/D mapping col=lane&15, row=(lane>>4)*4+r  [m89-verified]
#pragma unroll
  for (int i = 0; i < 4; ++i) {
#pragma unroll
    for (int j = 0; j < 4; ++j) {
      const int gcol = n0 + wn * 64 + j * 16 + fr;
      const float bv = bias[(size_t)e * N + gcol];
#pragma unroll
      for (int r = 0; r < 4; ++r) {
        const int gm = m0 + wm * 64 + i * 16 + (lane >> 4) * 4 + r;
        if (gm < cnt) {
          float v = acc[i][j][r] + bv;
          if (GELU) v = 0.5f * v * (1.0f + erff(v * 0.70710678118654752f));
          if (OUTBF)
            ((__hip_bfloat16*)Cout)[(size_t)(seg + gm) * N + gcol] = __float2bfloat16(v);
          else
            ((float*)Cout)[(size_t)(seg + gm) * N + gcol] = v;
        }
      }
    }
  }
}

// out[t] = g0*y[slot0] + g1*y[slot1]
__global__ void k_combine(const float* __restrict__ ybuf, const int* __restrict__ slot_of,
                          const float* __restrict__ gates, float* __restrict__ out)
{
  const int t = blockIdx.x;
  const int s0 = slot_of[2*t], s1 = slot_of[2*t+1];
  const float g0 = gates[2*t], g1 = gates[2*t+1];
  const float4 a = ((const float4*)(ybuf + (size_t)s0 * EMB))[threadIdx.x];
  const float4 b = ((const float4*)(ybuf + (size_t)s1 * EMB))[threadIdx.x];
  float4 o;
  o.x = g0 * a.x + g1 * b.x;
  o.y = g0 * a.y + g1 * b.y;
  o.z = g0 * a.z + g1 * b.z;
  o.w = g0 * a.w + g1 * b.w;
  ((float4*)(out + (size_t)t * EMB))[threadIdx.x] = o;
}

// ---------------- launch ----------------

extern "C" void kernel_launch(void* const* d_in, const int* in_sizes, int n_in,
                              void* d_out, int out_size, void* d_ws, size_t ws_size,
                              hipStream_t stream)
{
  const float* x  = (const float*)d_in[0];
  const float* Wg = (const float*)d_in[1];
  const float* bg = (const float*)d_in[2];
  const float* W1 = (const float*)d_in[3];
  const float* b1 = (const float*)d_in[4];
  const float* W2 = (const float*)d_in[5];
  const float* b2 = (const float*)d_in[6];
  const float* W3 = (const float*)d_in[7];
  const float* b3 = (const float*)d_in[8];
  float* out = (float*)d_out;

  char* ws = (char*)d_ws;
  size_t off = 0;
  auto alloc = [&](size_t bytes) -> void* {
    void* p = ws + off;
    off = (off + bytes + 255) & ~(size_t)255;
    return p;
  };

  int*   counts    = (int*)alloc(NE * 4);
  int*   fill      = (int*)alloc(NE * 4);
  int*   offsets   = (int*)alloc((NE + 1) * 4);
  int*   eidx      = (int*)alloc((size_t)TOK * 2 * 4);
  float* gates     = (float*)alloc((size_t)TOK * 2 * 4);
  int*   slot_of   = (int*)alloc((size_t)TOK * 2 * 4);
  int*   route_tok = (int*)alloc((size_t)SLOTS * 4);
  __hip_bfloat16* Wb1 = (__hip_bfloat16*)alloc((size_t)NE * EMB  * HID  * 2);
  __hip_bfloat16* Wb2 = (__hip_bfloat16*)alloc((size_t)NE * HID  * HID2 * 2);
  __hip_bfloat16* Wb3 = (__hip_bfloat16*)alloc((size_t)NE * HID2 * EMB  * 2);
  __hip_bfloat16* xg  = (__hip_bfloat16*)alloc((size_t)(SLOTS + SLACK) * EMB  * 2);
  __hip_bfloat16* h1  = (__hip_bfloat16*)alloc((size_t)(SLOTS + SLACK) * HID  * 2);
  __hip_bfloat16* h2  = (__hip_bfloat16*)alloc((size_t)(SLOTS + SLACK) * HID2 * 2);
  float*          ybuf = (float*)alloc((size_t)(SLOTS + SLACK) * EMB * 4);
  (void)ws_size; (void)in_sizes; (void)n_in; (void)out_size;

  k_init<<<1, 64, 0, stream>>>(counts, fill);
  k_gating<<<TOK / 4, 256, 0, stream>>>(x, Wg, bg, eidx, gates, counts);
  k_offsets<<<1, 1, 0, stream>>>(counts, offsets);
  k_route<<<TOK / 256, 256, 0, stream>>>(eidx, fill, offsets, route_tok, slot_of);
  k_gather<<<SLOTS, 192, 0, stream>>>(x, route_tok, xg);

  {
    dim3 b(32, 8);
    k_transpose<<<dim3(HID  / 32, EMB  / 32, NE), b, 0, stream>>>(W1, Wb1, EMB,  HID);
    k_transpose<<<dim3(HID2 / 32, HID  / 32, NE), b, 0, stream>>>(W2, Wb2, HID,  HID2);
    k_transpose<<<dim3(EMB  / 32, HID2 / 32, NE), b, 0, stream>>>(W3, Wb3, HID2, EMB);
  }

  ffn_gemm<true,  true ><<<dim3(HID  / 128, TOK / 128, NE), 256, 0, stream>>>(xg, Wb1, b1, h1,   counts, offsets, EMB,  HID);
  ffn_gemm<true,  true ><<<dim3(HID2 / 128, TOK / 128, NE), 256, 0, stream>>>(h1, Wb2, b2, h2,   counts, offsets, HID,  HID2);
  ffn_gemm<false, false><<<dim3(EMB  / 128, TOK / 128, NE), 256, 0, stream>>>(h2, Wb3, b3, ybuf, counts, offsets, HID2, EMB);

  k_combine<<<TOK, 192, 0, stream>>>(ybuf, slot_of, gates, out);
}

// Round 2
// 3035.673 us; speedup vs baseline: 1.2316x; 1.2316x over previous
//
#include <hip/hip_runtime.h>
#include <hip/hip_bf16.h>

#define EMB 768
#define HID 3072
#define HID2 6144
#define NE 8
#define TOK 16384    // B*N = 8*2048
#define SLOTS 32768  // TOK * top-2
#define SLACK 256    // tail-read slack rows (M-tile 256 may overrun by 255)

typedef __attribute__((ext_vector_type(8))) short bf16x8;
typedef __attribute__((ext_vector_type(4))) float f32x4;

__device__ __forceinline__ unsigned short bfbits(float f) {
  __hip_bfloat16 h = __float2bfloat16(f);
  return __builtin_bit_cast(unsigned short, h);
}

// ---------------- init / gating / routing ----------------

__global__ void k_init(int* counts, int* fill) {
  if (threadIdx.x < NE) { counts[threadIdx.x] = 0; fill[threadIdx.x] = 0; }
}

__global__ __launch_bounds__(256) void k_gating(
    const float* __restrict__ x, const float* __restrict__ Wg,
    const float* __restrict__ bg, int* __restrict__ eidx,
    float* __restrict__ gates, int* __restrict__ counts)
{
  const int wave = threadIdx.x >> 6, lane = threadIdx.x & 63;
  const int t = blockIdx.x * 4 + wave;
  const float* xr = x + (size_t)t * EMB;
  float p[NE];
#pragma unroll
  for (int e = 0; e < NE; ++e) p[e] = 0.f;
  for (int k = lane; k < EMB; k += 64) {
    const float xv = xr[k];
    const float* wr = Wg + (size_t)k * NE;
#pragma unroll
    for (int e = 0; e < NE; ++e) p[e] += xv * wr[e];
  }
#pragma unroll
  for (int e = 0; e < NE; ++e) {
#pragma unroll
    for (int o = 32; o > 0; o >>= 1) p[e] += __shfl_xor(p[e], o);
    p[e] += bg[e];
  }
  float v0 = -1e30f, v1 = -1e30f; int i0 = 0, i1 = 0;
#pragma unroll
  for (int e = 0; e < NE; ++e) {
    const float v = p[e];
    if (v > v0)      { v1 = v0; i1 = i0; v0 = v; i0 = e; }
    else if (v > v1) { v1 = v;  i1 = e; }
  }
  const float ex = expf(v1 - v0);
  const float g0 = 1.f / (1.f + ex);
  const float g1 = 1.f - g0;
  if (lane == 0) {
    eidx[2*t] = i0; eidx[2*t+1] = i1;
    gates[2*t] = g0; gates[2*t+1] = g1;
    atomicAdd(&counts[i0], 1);
    atomicAdd(&counts[i1], 1);
  }
}

__global__ void k_offsets(const int* __restrict__ counts, int* __restrict__ offsets) {
  offsets[0] = 0;
  for (int e = 0; e < NE; ++e) offsets[e+1] = offsets[e] + counts[e];
}

__global__ void k_route(const int* __restrict__ eidx, int* __restrict__ fill,
                        const int* __restrict__ offsets, int* __restrict__ route_tok,
                        int* __restrict__ slot_of)
{
  const int t = blockIdx.x * 256 + threadIdx.x;
  if (t >= TOK) return;
#pragma unroll
  for (int k = 0; k < 2; ++k) {
    const int e = eidx[2*t + k];
    const int pos = atomicAdd(&fill[e], 1);
    const int slot = offsets[e] + pos;
    route_tok[slot] = t;
    slot_of[2*t + k] = slot;
  }
}

__global__ void k_gather(const float* __restrict__ x, const int* __restrict__ route_tok,
                         __hip_bfloat16* __restrict__ xg)
{
  const int s = blockIdx.x;
  const int t = route_tok[s];
  const float4 v = ((const float4*)(x + (size_t)t * EMB))[threadIdx.x];
  ushort4 u;
  u.x = bfbits(v.x); u.y = bfbits(v.y); u.z = bfbits(v.z); u.w = bfbits(v.w);
  *(ushort4*)((unsigned short*)xg + (size_t)s * EMB + threadIdx.x * 4) = u;
}

// fp32 [K,N] -> bf16 [N,K]  (per expert, LDS-tiled transpose)
__global__ void k_transpose(const float* __restrict__ W, __hip_bfloat16* __restrict__ Wt,
                            int K, int N)
{
  __shared__ float tile[32][33];
  const int e = blockIdx.z;
  const float* Wp = W + (size_t)e * K * N;
  __hip_bfloat16* Wtp = Wt + (size_t)e * K * N;
  const int n0 = blockIdx.x * 32, k0 = blockIdx.y * 32;
  for (int r = threadIdx.y; r < 32; r += 8)
    tile[r][threadIdx.x] = Wp[(size_t)(k0 + r) * N + n0 + threadIdx.x];
  __syncthreads();
  for (int r = threadIdx.y; r < 32; r += 8)
    Wtp[(size_t)(n0 + r) * K + k0 + threadIdx.x] = __float2bfloat16(tile[threadIdx.x][r]);
}

// ---------------- 256x256 8-phase MFMA GEMM ----------------
// A: bf16 [slots, K] row-major (per-expert segments); Bt: bf16 [NE, N, K].
// BM=BN=256, BK=64, 8 waves (2M x 4N), per-wave 128x64 C.
// LDS 128 KiB: [slot(2)][ A(2x16KB halves) | B(2x16KB halves) ].
// Row-XOR swizzle (byte ^= (row&7)<<4) applied on global SOURCE (linear
// global_load_lds dest) and on ds_read addresses.

#define BARRIER() asm volatile("s_barrier" ::: "memory")

template<bool GELU, bool OUTBF>
__global__ __launch_bounds__(512, 2) void ffn_gemm8(
    const __hip_bfloat16* __restrict__ A,
    const __hip_bfloat16* __restrict__ Bt,
    const float* __restrict__ bias,
    void* __restrict__ Cout,
    const int* __restrict__ counts,
    const int* __restrict__ offsets,
    int K, int N)
{
  const int e = blockIdx.z;
  const int cnt = counts[e];
  const int m0 = blockIdx.y * 256;
  if (m0 >= cnt) return;
  const int seg = offsets[e];
  const int n0 = blockIdx.x * 256;

  __shared__ char lds[131072];

  const int tid = threadIdx.x;
  const int wave = tid >> 6, lane = tid & 63;
  const int wm = wave >> 2, wn = wave & 3;

  const size_t KB = (size_t)K * 2;           // row stride bytes
  const char* Ag = (const char*)(A + (size_t)(seg + m0) * K);
  const char* Bg = (const char*)(Bt + (size_t)e * N * K + (size_t)n0 * K);

  // staging coords: thread covers LDS-linear bytes tid*16 (+8192), row = off>>7
  const int s_r0 = tid >> 3;                         // 0..63 (li=0); li=1 adds 64
  const int s_cb = ((tid & 7) * 16) ^ ((s_r0 & 7) << 4);  // (r+64)&7 == r&7

  auto stage_half = [&](const char* gh, int kbyte, int ldsoff) {
    __builtin_amdgcn_global_load_lds(
        (const __attribute__((address_space(1))) void*)(gh + (size_t)s_r0 * KB + kbyte + s_cb),
        (__attribute__((address_space(3))) void*)(lds + ldsoff + wave * 1024), 16, 0, 0);
    __builtin_amdgcn_global_load_lds(
        (const __attribute__((address_space(1))) void*)(gh + (size_t)(s_r0 + 64) * KB + kbyte + s_cb),
        (__attribute__((address_space(3))) void*)(lds + ldsoff + 8192 + wave * 1024), 16, 0, 0);
  };

  // fragment read constants
  const int fr  = lane & 15;
  const int fkb = (lane >> 4) * 16;      // byte offset of the 8-element k-slice
  const int xr  = (fr & 7) << 4;         // row-XOR (row%8 == fr%8 for all frags)
  const int rbb = (wn & 1) * 64;         // B local row base within its half

  f32x4 acc[8][4];
#pragma unroll
  for (int i = 0; i < 8; ++i)
#pragma unroll
    for (int j = 0; j < 4; ++j)
      acc[i][j] = (f32x4){0.f, 0.f, 0.f, 0.f};

  const int KT = K >> 6;

  // ---- prologue: tile0 (A0,A1,B0,B1) -> slot0 ; tile1 (B0,B1) -> slot1
  stage_half(Ag,              0, 0);
  stage_half(Ag + 128 * KB,   0, 16384);
  stage_half(Bg,              0, 32768);
  stage_half(Bg + 128 * KB,   0, 32768 + 16384);
  stage_half(Bg,              128, 65536 + 32768);
  stage_half(Bg + 128 * KB,   128, 65536 + 32768 + 16384);
  asm volatile("s_waitcnt vmcnt(4)" ::: "memory");   // tile0's 8 loads complete
  __builtin_amdgcn_sched_barrier(0);
  BARRIER();

  bf16x8 a[4][2], b[4][2];

  for (int kt = 0; kt < KT; ++kt) {
    const int slot = kt & 1;
    const char* Als = lds + slot * 65536 + wm * 16384;
    const char* Bls = lds + slot * 65536 + 32768 + (wn >> 1) * 16384;
    const int sl1 = (slot ^ 1) * 65536;
    const int sl0 = slot * 65536;
    const int kbA = (kt + 1 < KT ? kt + 1 : KT - 1) * 128;
    const int kbB = (kt + 2 < KT ? kt + 2 : KT - 1) * 128;

    // ---- phase 1: read a[0..3], b[0..1]; stage A0(t+1); MFMA quad(0,0)
#pragma unroll
    for (int m = 0; m < 4; ++m)
#pragma unroll
      for (int kh = 0; kh < 2; ++kh)
        a[m][kh] = *(const bf16x8*)(Als + (m * 16 + fr) * 128 + ((kh * 64 + fkb) ^ xr));
#pragma unroll
    for (int n = 0; n < 2; ++n)
#pragma unroll
      for (int kh = 0; kh < 2; ++kh)
        b[n][kh] = *(const bf16x8*)(Bls + (rbb + n * 16 + fr) * 128 + ((kh * 64 + fkb) ^ xr));
    stage_half(Ag, kbA, sl1);
    BARRIER();
    __builtin_amdgcn_s_setprio(1);
#pragma unroll
    for (int m = 0; m < 4; ++m)
#pragma unroll
      for (int n = 0; n < 2; ++n)
#pragma unroll
        for (int kh = 0; kh < 2; ++kh)
          acc[m][n] = __builtin_amdgcn_mfma_f32_16x16x32_bf16(a[m][kh], b[n][kh], acc[m][n], 0, 0, 0);
    __builtin_amdgcn_s_setprio(0);
    BARRIER();

    // ---- phase 2: read b[2..3]; stage A1(t+1); MFMA quad(0,1)
#pragma unroll
    for (int n = 2; n < 4; ++n)
#pragma unroll
      for (int kh = 0; kh < 2; ++kh)
        b[n][kh] = *(const bf16x8*)(Bls + (rbb + n * 16 + fr) * 128 + ((kh * 64 + fkb) ^ xr));
    stage_half(Ag + 128 * KB, kbA, sl1 + 16384);
    BARRIER();
    __builtin_amdgcn_s_setprio(1);
#pragma unroll
    for (int m = 0; m < 4; ++m)
#pragma unroll
      for (int n = 0; n < 2; ++n)
#pragma unroll
        for (int kh = 0; kh < 2; ++kh)
          acc[m][n + 2] = __builtin_amdgcn_mfma_f32_16x16x32_bf16(a[m][kh], b[n + 2][kh], acc[m][n + 2], 0, 0, 0);
    __builtin_amdgcn_s_setprio(0);
    BARRIER();

    // ---- phase 3: read a[4..7]; stage B0(t+2) into current slot (B reads done); MFMA quad(1,0)
#pragma unroll
    for (int m = 0; m < 4; ++m)
#pragma unroll
      for (int kh = 0; kh < 2; ++kh)
        a[m][kh] = *(const bf16x8*)(Als + ((m + 4) * 16 + fr) * 128 + ((kh * 64 + fkb) ^ xr));
    stage_half(Bg, kbB, sl0 + 32768);
    BARRIER();
    __builtin_amdgcn_s_setprio(1);
#pragma unroll
    for (int m = 0; m < 4; ++m)
#pragma unroll
      for (int n = 0; n < 2; ++n)
#pragma unroll
        for (int kh = 0; kh < 2; ++kh)
          acc[m + 4][n] = __builtin_amdgcn_mfma_f32_16x16x32_bf16(a[m][kh], b[n][kh], acc[m + 4][n], 0, 0, 0);
    __builtin_amdgcn_s_setprio(0);
    BARRIER();

    // ---- phase 4: stage B1(t+2); vmcnt(4) -> tile t+1 fully staged; MFMA quad(1,1)
    stage_half(Bg + 128 * KB, kbB, sl0 + 32768 + 16384);
    asm volatile("s_waitcnt vmcnt(4)" ::: "memory");
    __builtin_amdgcn_sched_barrier(0);
    BARRIER();
    __builtin_amdgcn_s_setprio(1);
#pragma unroll
    for (int m = 0; m < 4; ++m)
#pragma unroll
      for (int n = 0; n < 2; ++n)
#pragma unroll
        for (int kh = 0; kh < 2; ++kh)
          acc[m + 4][n + 2] = __builtin_amdgcn_mfma_f32_16x16x32_bf16(a[m][kh], b[n + 2][kh], acc[m + 4][n + 2], 0, 0, 0);
    __builtin_amdgcn_s_setprio(0);
    BARRIER();
  }

  // ---- epilogue: C/D map col=lane&15, row=(lane>>4)*4+r  [m89-verified]
#pragma unroll
  for (int mf = 0; mf < 8; ++mf) {
    const int gmb = m0 + wm * 128 + mf * 16 + (lane >> 4) * 4;
#pragma unroll
    for (int nf = 0; nf < 4; ++nf) {
      const int gcol = n0 + wn * 64 + nf * 16 + fr;
      const float bv = bias[(size_t)e * N + gcol];
#pragma unroll
      for (int r = 0; r < 4; ++r) {
        const int gm = gmb + r;
        if (gm < cnt) {
          float v = acc[mf][nf][r] + bv;
          if (GELU) v = 0.5f * v * (1.0f + erff(v * 0.70710678118654752f));
          if (OUTBF)
            ((__hip_bfloat16*)Cout)[(size_t)(seg + gm) * N + gcol] = __float2bfloat16(v);
          else
            ((float*)Cout)[(size_t)(seg + gm) * N + gcol] = v;
        }
      }
    }
  }
}

// out[t] = g0*y[slot0] + g1*y[slot1]
__global__ void k_combine(const float* __restrict__ ybuf, const int* __restrict__ slot_of,
                          const float* __restrict__ gates, float* __restrict__ out)
{
  const int t = blockIdx.x;
  const int s0 = slot_of[2*t], s1 = slot_of[2*t+1];
  const float g0 = gates[2*t], g1 = gates[2*t+1];
  const float4 a = ((const float4*)(ybuf + (size_t)s0 * EMB))[threadIdx.x];
  const float4 b = ((const float4*)(ybuf + (size_t)s1 * EMB))[threadIdx.x];
  float4 o;
  o.x = g0 * a.x + g1 * b.x;
  o.y = g0 * a.y + g1 * b.y;
  o.z = g0 * a.z + g1 * b.z;
  o.w = g0 * a.w + g1 * b.w;
  ((float4*)(out + (size_t)t * EMB))[threadIdx.x] = o;
}

// ---------------- launch ----------------

extern "C" void kernel_launch(void* const* d_in, const int* in_sizes, int n_in,
                              void* d_out, int out_size, void* d_ws, size_t ws_size,
                              hipStream_t stream)
{
  const float* x  = (const float*)d_in[0];
  const float* Wg = (const float*)d_in[1];
  const float* bg = (const float*)d_in[2];
  const float* W1 = (const float*)d_in[3];
  const float* b1 = (const float*)d_in[4];
  const float* W2 = (const float*)d_in[5];
  const float* b2 = (const float*)d_in[6];
  const float* W3 = (const float*)d_in[7];
  const float* b3 = (const float*)d_in[8];
  float* out = (float*)d_out;

  char* ws = (char*)d_ws;
  size_t off = 0;
  auto alloc = [&](size_t bytes) -> void* {
    void* p = ws + off;
    off = (off + bytes + 255) & ~(size_t)255;
    return p;
  };

  int*   counts    = (int*)alloc(NE * 4);
  int*   fill      = (int*)alloc(NE * 4);
  int*   offsets   = (int*)alloc((NE + 1) * 4);
  int*   eidx      = (int*)alloc((size_t)TOK * 2 * 4);
  float* gates     = (float*)alloc((size_t)TOK * 2 * 4);
  int*   slot_of   = (int*)alloc((size_t)TOK * 2 * 4);
  int*   route_tok = (int*)alloc((size_t)SLOTS * 4);
  __hip_bfloat16* Wb1 = (__hip_bfloat16*)alloc((size_t)NE * EMB  * HID  * 2);
  __hip_bfloat16* Wb2 = (__hip_bfloat16*)alloc((size_t)NE * HID  * HID2 * 2);
  __hip_bfloat16* Wb3 = (__hip_bfloat16*)alloc((size_t)NE * HID2 * EMB  * 2);
  __hip_bfloat16* xg  = (__hip_bfloat16*)alloc((size_t)(SLOTS + SLACK) * EMB  * 2);
  __hip_bfloat16* h1  = (__hip_bfloat16*)alloc((size_t)(SLOTS + SLACK) * HID  * 2);
  __hip_bfloat16* h2  = (__hip_bfloat16*)alloc((size_t)(SLOTS + SLACK) * HID2 * 2);
  float*          ybuf = (float*)alloc((size_t)(SLOTS + SLACK) * EMB * 4);
  (void)ws_size; (void)in_sizes; (void)n_in; (void)out_size;

  k_init<<<1, 64, 0, stream>>>(counts, fill);
  k_gating<<<TOK / 4, 256, 0, stream>>>(x, Wg, bg, eidx, gates, counts);
  k_offsets<<<1, 1, 0, stream>>>(counts, offsets);
  k_route<<<TOK / 256, 256, 0, stream>>>(eidx, fill, offsets, route_tok, slot_of);
  k_gather<<<SLOTS, 192, 0, stream>>>(x, route_tok, xg);

  {
    dim3 b(32, 8);
    k_transpose<<<dim3(HID  / 32, EMB  / 32, NE), b, 0, stream>>>(W1, Wb1, EMB,  HID);
    k_transpose<<<dim3(HID2 / 32, HID  / 32, NE), b, 0, stream>>>(W2, Wb2, HID,  HID2);
    k_transpose<<<dim3(EMB  / 32, HID2 / 32, NE), b, 0, stream>>>(W3, Wb3, HID2, EMB);
  }

  ffn_gemm8<true,  true ><<<dim3(HID  / 256, SLOTS / 256, NE), 512, 0, stream>>>(xg, Wb1, b1, h1,   counts, offsets, EMB,  HID);
  ffn_gemm8<true,  true ><<<dim3(HID2 / 256, SLOTS / 256, NE), 512, 0, stream>>>(h1, Wb2, b2, h2,   counts, offsets, HID,  HID2);
  ffn_gemm8<false, false><<<dim3(EMB  / 256, SLOTS / 256, NE), 512, 0, stream>>>(h2, Wb3, b3, ybuf, counts, offsets, HID2, EMB);

  k_combine<<<TOK, 192, 0, stream>>>(ybuf, slot_of, gates, out);
}